// Round 11
// baseline (288.825 us; speedup 1.0000x reference)
//
#include <hip/hip_runtime.h>

// GTConv autoencoder, MI355X. Round-9 kernel, resubmitted (rounds 9/10 were
// GPU-acquisition infrastructure failures; never measured).
// Mono-kernel: r6 grid-barrier structure (PASS) + r8 1-RT split-dot bodies
// (PASS, absmax 3e-5).
// Math (PASS r2..r8): S^k x[t] = sum_{d,p} c[k][d][p] Sg^p x[t-d] (cyclic);
// Y[t,m,o] = sum_i sum_{d,p} g[o,i,d,p] Zp[t-d,i,m]; Z1=Sg x, Z2=Sg^2 x.
//
// 192 blocks x 768 threads, 1 block/CU co-resident; 4 grid barriers.
// Every phase: all global loads issued in 1-2 independent batches -> LDS reduce.
//
// ws (float offsets): SgTp 0 (36864) | Sg2Tp 36864 | XT 73728 (6144)
//  G 79872: GE1@79872(192) GE2@80064(6144) GD1@86208(6144) GD2@92352(192)
//  ZB1 104832 (49152) | ZB2 153984 | ZA1 203136 (98304) | ZA2 301440
//  ZC1 399744 (98304) | ZC2 498048 | B1 596352 | B2 645504 | B3 694656 (49152 ea)
//  BAR @ 743808 (unsigned cells, 128B apart)

#define NODES 192
#define NBLK 192
typedef float4 f4;

__device__ __forceinline__ void compute_c(const float* __restrict__ s, float c[3][3][3]) {
    const float s00 = s[0], s01 = s[1], s10 = s[2], s11 = s[3];
    #pragma unroll
    for (int k = 0; k < 3; ++k)
        #pragma unroll
        for (int d = 0; d < 3; ++d)
            #pragma unroll
            for (int p = 0; p < 3; ++p) c[k][d][p] = 0.f;
    c[0][0][0] = 1.f;
    c[1][0][0] = s00; c[1][0][1] = s01;
    c[1][1][0] = s10; c[1][1][1] = s11;
    c[2][0][0] = s00 * s00;       c[2][0][1] = 2.f * s00 * s01;               c[2][0][2] = s01 * s01;
    c[2][1][0] = 2.f * s00 * s10; c[2][1][1] = 2.f * (s00 * s11 + s01 * s10); c[2][1][2] = 2.f * s11 * s01;
    c[2][2][0] = s10 * s10;       c[2][2][1] = 2.f * s10 * s11;               c[2][2][2] = s11 * s11;
}

__device__ __forceinline__ void gridbar(unsigned* cell) {
    __syncthreads();
    if (threadIdx.x == 0) {
        __threadfence();
        const unsigned got = atomicAdd(cell, 1u) + 1u;
        if (got != (unsigned)NBLK) {
            while (__hip_atomic_load(cell, __ATOMIC_RELAXED, __HIP_MEMORY_SCOPE_AGENT)
                   != (unsigned)NBLK)
                __builtin_amdgcn_s_sleep(8);
        }
    }
    __syncthreads();
    __threadfence();
}

__global__ __launch_bounds__(768) void mono_kernel(
        const float* __restrict__ X, const float* __restrict__ Sg, const float* __restrict__ s,
        const float* __restrict__ he1, const float* __restrict__ he2,
        const float* __restrict__ hd1, const float* __restrict__ hd2,
        float* __restrict__ out, float* __restrict__ ws) {
    const int b = blockIdx.x, tid = threadIdx.x;
    const int m = tid % NODES, q = tid / NODES;     // q in 0..3

    float* SgTp  = ws;
    float* Sg2Tp = ws + 36864;
    float* XT    = ws + 73728;
    float* G     = ws + 79872;
    float* GE1 = G, *GE2 = G + 192, *GD1 = G + 6336, *GD2 = G + 12480;
    float* ZB1 = ws + 104832, *ZB2 = ws + 153984;
    float* ZA1 = ws + 203136, *ZA2 = ws + 301440;
    float* ZC1 = ws + 399744, *ZC2 = ws + 498048;
    float* B1  = ws + 596352, *B2 = ws + 645504, *B3 = ws + 694656;
    unsigned* bars = (unsigned*)(ws + 743808);
    const f4* Ap = (const f4*)SgTp;
    const f4* Bp = (const f4*)Sg2Tp;

    __shared__ __align__(16) float sm_x[4 * NODES];
    __shared__ __align__(16) float sm_v[4 * NODES];
    __shared__ __align__(16) float sm_zx1[4 * NODES];
    __shared__ __align__(16) float sm_zx2[4 * NODES];
    __shared__ __align__(16) float sm_g[1536];
    __shared__ __align__(16) float sm_ps[6144];

    // ---- ready-gate (barrier cells valid regardless of 0xAA poison) ----
    if (tid == 0) {
        if (b == 0) {
            for (int k = 0; k < 5; ++k) atomicExch(&bars[k * 32], 0u);
            __threadfence();
            atomicExch(&bars[5 * 32], 0x900DBEEFu);
        } else {
            while (__hip_atomic_load(&bars[5 * 32], __ATOMIC_RELAXED, __HIP_MEMORY_SCOPE_AGENT)
                   != 0x900DBEEFu)
                __builtin_amdgcn_s_sleep(8);
        }
    }
    __syncthreads();
    __threadfence();

    // =============== P0: SgT pack + Sg^2 (row b); b0: g tables; b1: XT ===============
    {
        if (tid < NODES) {
            const float v = Sg[b * NODES + tid];
            sm_x[tid] = v;
            SgTp[(tid >> 2) * 768 + b * 4 + (tid & 3)] = v;
        }
        __syncthreads();
        {   // Sg^2[b][n], n=m, 4-way split over r
            float v[48];
            #pragma unroll
            for (int rr = 0; rr < 48; ++rr) v[rr] = Sg[(48 * q + rr) * NODES + m];
            float acc = 0.f;
            #pragma unroll
            for (int rr = 0; rr < 48; ++rr) acc += sm_x[48 * q + rr] * v[rr];
            sm_ps[q * NODES + m] = acc;
        }
        __syncthreads();
        if (q == 0) {
            const float s2 = sm_ps[m] + sm_ps[NODES + m] + sm_ps[2 * NODES + m] + sm_ps[3 * NODES + m];
            Sg2Tp[(m >> 2) * 768 + b * 4 + (m & 3)] = s2;
        }
        if (b == 0) {                       // g tables
            float c[3][3][3];
            compute_c(s, c);
            for (int w = tid; w < 1056; w += 768) {
                const float* hh; int gbase, pl;
                if (w < 16)        { hh = he1; gbase = 0;     pl = w; }
                else if (w < 528)  { hh = he2; gbase = 192;   pl = w - 16; }
                else if (w < 1040) { hh = hd1; gbase = 6336;  pl = w - 528; }
                else               { hh = hd2; gbase = 12480; pl = w - 1040; }
                const float h0 = hh[pl * 3], h1 = hh[pl * 3 + 1], h2 = hh[pl * 3 + 2];
                float* gp = G + gbase + pl * 12;
                #pragma unroll
                for (int dp = 0; dp < 12; ++dp) {
                    float val = 0.f;
                    if (dp < 9) { const int d = dp / 3, p = dp % 3;
                                  val = h0 * c[0][d][p] + h1 * c[1][d][p] + h2 * c[2][d][p]; }
                    gp[dp] = val;
                }
            }
        } else if (b == 1) {                // XT[t][n] = X[n][t]
            if (tid < NODES) {
                const f4* xr = (const f4*)(X + tid * 32);
                f4 vv[8];
                #pragma unroll
                for (int qq = 0; qq < 8; ++qq) vv[qq] = xr[qq];
                #pragma unroll
                for (int qq = 0; qq < 8; ++qq) {
                    XT[(4 * qq + 0) * NODES + tid] = vv[qq].x;
                    XT[(4 * qq + 1) * NODES + tid] = vv[qq].y;
                    XT[(4 * qq + 2) * NODES + tid] = vv[qq].z;
                    XT[(4 * qq + 3) * NODES + tid] = vv[qq].w;
                }
            }
        }
    }
    gridbar(&bars[0]);

    // =============== P1: e1 (+in-block Zx) -> B1; ZB GEMV -> ZB ===============
    if (b < 64) {
        const int tq = b & 15, o0 = (b >> 4) * 4;
        {   // stage 4 time rows of X
            const int u = (2 * tq + q - 2) & 31;
            sm_x[q * NODES + m] = XT[u * NODES + m];
        }
        if (tid < 48) sm_g[tid] = GE1[o0 * 12 + tid];
        __syncthreads();
        {   // Zx partial GEMV: thread (m,q) -> partials for 4 time slots
            f4 va[12], vb[12];
            #pragma unroll
            for (int j = 0; j < 12; ++j) va[j] = Ap[(12 * q + j) * NODES + m];
            #pragma unroll
            for (int j = 0; j < 12; ++j) vb[j] = Bp[(12 * q + j) * NODES + m];
            #pragma unroll
            for (int ch = 0; ch < 4; ++ch) {
                const f4* xr = (const f4*)(sm_x + ch * NODES);
                float a1 = 0.f, a2 = 0.f;
                #pragma unroll
                for (int j = 0; j < 12; ++j) {
                    const f4 x = xr[12 * q + j];
                    a1 += va[j].x * x.x + va[j].y * x.y + va[j].z * x.z + va[j].w * x.w;
                    a2 += vb[j].x * x.x + vb[j].y * x.y + vb[j].z * x.z + vb[j].w * x.w;
                }
                sm_ps[((0 * 4 + ch) * 4 + q) * NODES + m] = a1;
                sm_ps[((1 * 4 + ch) * 4 + q) * NODES + m] = a2;
            }
        }
        __syncthreads();
        {   // reduce -> sm_zx1/sm_zx2
            #pragma unroll
            for (int pp = 0; pp < 2; ++pp) {
                const int pi = q * 2 + pp, mat = pi >> 2, ch = pi & 3;
                float val = 0.f;
                #pragma unroll
                for (int qq = 0; qq < 4; ++qq)
                    val += sm_ps[((mat * 4 + ch) * 4 + qq) * NODES + m];
                (mat == 0 ? sm_zx1 : sm_zx2)[ch * NODES + m] = val;
            }
        }
        __syncthreads();
        {   // conv: thread (m, q=o-idx)
            float x0[4], z1[4], z2[4];
            #pragma unroll
            for (int dl = 0; dl < 4; ++dl) {
                x0[dl] = sm_x[dl * NODES + m];
                z1[dl] = sm_zx1[dl * NODES + m];
                z2[dl] = sm_zx2[dl * NODES + m];
            }
            const float* gr = &sm_g[q * 12];
            const f4 ga = *(const f4*)gr, gb = *(const f4*)(gr + 4), gc = *(const f4*)(gr + 8);
            float a[2];
            #pragma unroll
            for (int tt = 0; tt < 2; ++tt)
                a[tt] = ga.x * x0[tt + 2] + ga.y * z1[tt + 2] + ga.z * z2[tt + 2]
                      + ga.w * x0[tt + 1] + gb.x * z1[tt + 1] + gb.y * z2[tt + 1]
                      + gb.z * x0[tt]     + gb.w * z1[tt]     + gc.x * z2[tt];
            const float v = fmaxf(fmaxf(a[0], a[1]), 0.f);
            B1[(tq * 16 + o0 + q) * NODES + m] = v;
            sm_v[q * NODES + m] = v;
        }
        __syncthreads();
        {   // ZB partial GEMV on sm_v
            f4 va[12], vb[12];
            #pragma unroll
            for (int j = 0; j < 12; ++j) va[j] = Ap[(12 * q + j) * NODES + m];
            #pragma unroll
            for (int j = 0; j < 12; ++j) vb[j] = Bp[(12 * q + j) * NODES + m];
            #pragma unroll
            for (int ch = 0; ch < 4; ++ch) {
                const f4* xr = (const f4*)(sm_v + ch * NODES);
                float a1 = 0.f, a2 = 0.f;
                #pragma unroll
                for (int j = 0; j < 12; ++j) {
                    const f4 x = xr[12 * q + j];
                    a1 += va[j].x * x.x + va[j].y * x.y + va[j].z * x.z + va[j].w * x.w;
                    a2 += vb[j].x * x.x + vb[j].y * x.y + vb[j].z * x.z + vb[j].w * x.w;
                }
                sm_ps[((0 * 4 + ch) * 4 + q) * NODES + m] = a1;
                sm_ps[((1 * 4 + ch) * 4 + q) * NODES + m] = a2;
            }
        }
        __syncthreads();
        {
            #pragma unroll
            for (int pp = 0; pp < 2; ++pp) {
                const int pi = q * 2 + pp, mat = pi >> 2, ch = pi & 3;
                float val = 0.f;
                #pragma unroll
                for (int qq = 0; qq < 4; ++qq)
                    val += sm_ps[((mat * 4 + ch) * 4 + qq) * NODES + m];
                (mat == 0 ? ZB1 : ZB2)[(tq * 16 + o0 + ch) * NODES + m] = val;
            }
        }
    }
    gridbar(&bars[1 * 32]);

    // =============== P2: e2 conv -> B2; ZA GEMV (zero-stuffed) ===============
    if (b < 64) {
        const int q8 = b & 7, o0 = (b >> 3) * 4;
        for (int idx = tid; idx < 768; idx += 768) sm_g[idx] = GE2[(o0 * 16) * 12 + idx];
        {   // conv: thread (m, cq=q): 4 i's
            const int i0 = q * 4;
            float xv[4][4], z1v[4][4], z2v[4][4];
            #pragma unroll
            for (int dl = 0; dl < 4; ++dl) {
                const int u = (2 * q8 + dl - 2) & 15;
                const int base = (u * 16 + i0) * NODES + m;
                #pragma unroll
                for (int ii = 0; ii < 4; ++ii) xv[dl][ii]  = B1[base + ii * NODES];
                #pragma unroll
                for (int ii = 0; ii < 4; ++ii) z1v[dl][ii] = ZB1[base + ii * NODES];
                #pragma unroll
                for (int ii = 0; ii < 4; ++ii) z2v[dl][ii] = ZB2[base + ii * NODES];
            }
            __syncthreads();   // sm_g ready
            #pragma unroll
            for (int o = 0; o < 4; ++o) {
                float a[2] = {0.f, 0.f};
                #pragma unroll
                for (int ii = 0; ii < 4; ++ii) {
                    const float* gr = &sm_g[(o * 16 + i0 + ii) * 12];
                    const f4 ga = *(const f4*)gr, gb = *(const f4*)(gr + 4), gc = *(const f4*)(gr + 8);
                    #pragma unroll
                    for (int tt = 0; tt < 2; ++tt)
                        a[tt] += ga.x * xv[tt + 2][ii] + ga.y * z1v[tt + 2][ii] + ga.z * z2v[tt + 2][ii]
                               + ga.w * xv[tt + 1][ii] + gb.x * z1v[tt + 1][ii] + gb.y * z2v[tt + 1][ii]
                               + gb.z * xv[tt][ii]     + gb.w * z1v[tt][ii]     + gc.x * z2v[tt][ii];
                }
                sm_ps[((q * 4 + o) * 2 + 0) * NODES + m] = a[0];
                sm_ps[((q * 4 + o) * 2 + 1) * NODES + m] = a[1];
            }
        }
        __syncthreads();
        {   // reduce + pool + relu: thread (m, q=o)
            float r0 = 0.f, r1 = 0.f;
            #pragma unroll
            for (int cq = 0; cq < 4; ++cq) {
                r0 += sm_ps[((cq * 4 + q) * 2 + 0) * NODES + m];
                r1 += sm_ps[((cq * 4 + q) * 2 + 1) * NODES + m];
            }
            const float v = fmaxf(fmaxf(r0, r1), 0.f);
            B2[(q8 * 32 + o0 + q) * NODES + m] = v;
            sm_v[q * NODES + m] = v;
        }
        __syncthreads();
        {   // ZA partial GEMV
            f4 va[12], vb[12];
            #pragma unroll
            for (int j = 0; j < 12; ++j) va[j] = Ap[(12 * q + j) * NODES + m];
            #pragma unroll
            for (int j = 0; j < 12; ++j) vb[j] = Bp[(12 * q + j) * NODES + m];
            #pragma unroll
            for (int ch = 0; ch < 4; ++ch) {
                const f4* xr = (const f4*)(sm_v + ch * NODES);
                float a1 = 0.f, a2 = 0.f;
                #pragma unroll
                for (int j = 0; j < 12; ++j) {
                    const f4 x = xr[12 * q + j];
                    a1 += va[j].x * x.x + va[j].y * x.y + va[j].z * x.z + va[j].w * x.w;
                    a2 += vb[j].x * x.x + vb[j].y * x.y + vb[j].z * x.z + vb[j].w * x.w;
                }
                sm_ps[((0 * 4 + ch) * 4 + q) * NODES + m] = a1;
                sm_ps[((1 * 4 + ch) * 4 + q) * NODES + m] = a2;
            }
        }
        __syncthreads();
        {
            const int t2 = 2 * q8;
            #pragma unroll
            for (int pp = 0; pp < 2; ++pp) {
                const int pi = q * 2 + pp, mat = pi >> 2, ch = pi & 3;
                float val = 0.f;
                #pragma unroll
                for (int qq = 0; qq < 4; ++qq)
                    val += sm_ps[((mat * 4 + ch) * 4 + qq) * NODES + m];
                float* Z = (mat == 0) ? ZA1 : ZA2;
                Z[(t2 * 32 + o0 + ch) * NODES + m] = val;
                Z[((t2 + 1) * 32 + o0 + ch) * NODES + m] = 0.f;
            }
        }
    }
    gridbar(&bars[2 * 32]);

    // =============== P3: d1 conv -> B3 raw; ZC GEMV (zero-stuffed) ===============
    if (b < 64) {
        const int t16 = b & 15, o0 = (b >> 4) * 4;
        for (int idx = tid; idx < 1536; idx += 768) sm_g[idx] = GD1[(o0 * 32) * 12 + idx];
        __syncthreads();
        {   // conv: thread (m, cq=q): 8 i's in 2 chunks of 4
            float acc[4] = {0.f, 0.f, 0.f, 0.f};
            #pragma unroll
            for (int cc = 0; cc < 2; ++cc) {
                const int i0 = cc * 16 + q * 4;
                float xv[3][4], z1v[3][4], z2v[3][4];
                #pragma unroll
                for (int dl = 0; dl < 3; ++dl) {
                    const int u = (t16 + dl - 2) & 15;
                    const float msk = (u & 1) ? 0.f : 1.f;
                    const int sb = ((u >> 1) * 32 + i0) * NODES + m;
                    const int zb = (u * 32 + i0) * NODES + m;
                    #pragma unroll
                    for (int ii = 0; ii < 4; ++ii) xv[dl][ii]  = B2[sb + ii * NODES] * msk;  // B2>=0
                    #pragma unroll
                    for (int ii = 0; ii < 4; ++ii) z1v[dl][ii] = ZA1[zb + ii * NODES];
                    #pragma unroll
                    for (int ii = 0; ii < 4; ++ii) z2v[dl][ii] = ZA2[zb + ii * NODES];
                }
                #pragma unroll
                for (int o = 0; o < 4; ++o)
                    #pragma unroll
                    for (int ii = 0; ii < 4; ++ii) {
                        const float* gr = &sm_g[(o * 32 + i0 + ii) * 12];
                        const f4 ga = *(const f4*)gr, gb = *(const f4*)(gr + 4), gc = *(const f4*)(gr + 8);
                        acc[o] += ga.x * xv[2][ii] + ga.y * z1v[2][ii] + ga.z * z2v[2][ii]
                                + ga.w * xv[1][ii] + gb.x * z1v[1][ii] + gb.y * z2v[1][ii]
                                + gb.z * xv[0][ii] + gb.w * z1v[0][ii] + gc.x * z2v[0][ii];
                    }
            }
            #pragma unroll
            for (int o = 0; o < 4; ++o) sm_ps[(q * 4 + o) * NODES + m] = acc[o];
        }
        __syncthreads();
        {   // reduce: thread (m, q=o)
            const float raw = sm_ps[(0 * 4 + q) * NODES + m] + sm_ps[(1 * 4 + q) * NODES + m]
                            + sm_ps[(2 * 4 + q) * NODES + m] + sm_ps[(3 * 4 + q) * NODES + m];
            B3[(t16 * 16 + o0 + q) * NODES + m] = raw;
            sm_v[q * NODES + m] = fmaxf(raw, 0.f);
        }
        __syncthreads();
        {   // ZC partial GEMV
            f4 va[12], vb[12];
            #pragma unroll
            for (int j = 0; j < 12; ++j) va[j] = Ap[(12 * q + j) * NODES + m];
            #pragma unroll
            for (int j = 0; j < 12; ++j) vb[j] = Bp[(12 * q + j) * NODES + m];
            #pragma unroll
            for (int ch = 0; ch < 4; ++ch) {
                const f4* xr = (const f4*)(sm_v + ch * NODES);
                float a1 = 0.f, a2 = 0.f;
                #pragma unroll
                for (int j = 0; j < 12; ++j) {
                    const f4 x = xr[12 * q + j];
                    a1 += va[j].x * x.x + va[j].y * x.y + va[j].z * x.z + va[j].w * x.w;
                    a2 += vb[j].x * x.x + vb[j].y * x.y + vb[j].z * x.z + vb[j].w * x.w;
                }
                sm_ps[((0 * 4 + ch) * 4 + q) * NODES + m] = a1;
                sm_ps[((1 * 4 + ch) * 4 + q) * NODES + m] = a2;
            }
        }
        __syncthreads();
        {
            const int t2 = 2 * t16;
            #pragma unroll
            for (int pp = 0; pp < 2; ++pp) {
                const int pi = q * 2 + pp, mat = pi >> 2, ch = pi & 3;
                float val = 0.f;
                #pragma unroll
                for (int qq = 0; qq < 4; ++qq)
                    val += sm_ps[((mat * 4 + ch) * 4 + qq) * NODES + m];
                float* Z = (mat == 0) ? ZC1 : ZC2;
                Z[(t2 * 16 + o0 + ch) * NODES + m] = val;
                Z[((t2 + 1) * 16 + o0 + ch) * NODES + m] = 0.f;
            }
        }
    }
    gridbar(&bars[3 * 32]);

    // =============== P4: d2 -> out[m*32+t] ===============
    if (b < 32) {
        const int t = b;
        if (tid < 192) sm_g[tid] = GD2[tid];
        {
            const int i0 = q * 4;
            float xv[3][4], z1v[3][4], z2v[3][4];
            #pragma unroll
            for (int dl = 0; dl < 3; ++dl) {
                const int u = (t + dl - 2) & 31;
                const float msk = (u & 1) ? 0.f : 1.f;
                const int sb = ((u >> 1) * 16 + i0) * NODES + m;
                const int zb = (u * 16 + i0) * NODES + m;
                #pragma unroll
                for (int ii = 0; ii < 4; ++ii) xv[dl][ii]  = fmaxf(B3[sb + ii * NODES], 0.f) * msk;
                #pragma unroll
                for (int ii = 0; ii < 4; ++ii) z1v[dl][ii] = ZC1[zb + ii * NODES];
                #pragma unroll
                for (int ii = 0; ii < 4; ++ii) z2v[dl][ii] = ZC2[zb + ii * NODES];
            }
            __syncthreads();   // sm_g ready
            float acc = 0.f;
            #pragma unroll
            for (int ii = 0; ii < 4; ++ii) {
                const float* gr = &sm_g[(i0 + ii) * 12];
                const f4 ga = *(const f4*)gr, gb = *(const f4*)(gr + 4), gc = *(const f4*)(gr + 8);
                acc += ga.x * xv[2][ii] + ga.y * z1v[2][ii] + ga.z * z2v[2][ii]
                     + ga.w * xv[1][ii] + gb.x * z1v[1][ii] + gb.y * z2v[1][ii]
                     + gb.z * xv[0][ii] + gb.w * z1v[0][ii] + gc.x * z2v[0][ii];
            }
            sm_ps[q * NODES + m] = acc;
        }
        __syncthreads();
        if (q == 0)
            out[m * 32 + t] = sm_ps[m] + sm_ps[NODES + m] + sm_ps[2 * NODES + m] + sm_ps[3 * NODES + m];
    }
}

extern "C" void kernel_launch(void* const* d_in, const int* in_sizes, int n_in,
                              void* d_out, int out_size, void* d_ws, size_t ws_size,
                              hipStream_t stream) {
    (void)in_sizes; (void)n_in; (void)out_size; (void)ws_size;
    const float* X   = (const float*)d_in[0];
    const float* Sg  = (const float*)d_in[1];
    const float* s   = (const float*)d_in[2];
    const float* he1 = (const float*)d_in[3];
    const float* he2 = (const float*)d_in[4];
    const float* hd1 = (const float*)d_in[5];
    const float* hd2 = (const float*)d_in[6];
    mono_kernel<<<NBLK, 768, 0, stream>>>(X, Sg, s, he1, he2, hd1, hd2,
                                          (float*)d_out, (float*)d_ws);
}

// Round 13
// 148.700 us; speedup vs baseline: 1.9423x; 1.9423x over previous
//
#include <hip/hip_runtime.h>

// GTConv autoencoder, MI355X. Round-12 kernel resubmitted (round-12 bench was a
// GPU-acquisition infrastructure failure; never measured).
// r9's HW-verified phase bodies (r11 PASS, absmax 3.05e-5) as 5 standalone
// kernels; grid barriers, fences, ready-gate deleted (r11: ~200us cost).
// Math: S^k x[t] = sum_{d,p} c[k][d][p] Sg^p x[t-d] (cyclic);
// Y[t,m,o] = sum_i sum_{d,p} g[o,i,d,p] Zp[t-d,i,m]; Z1=Sg x, Z2=Sg^2 x.
// Fusion: conv block (t-chunk, o-chunk) also computes next-layer Z for its
// own outputs from LDS (no cross-block dep); all loads in 1-2 batched RTs.
//
// ws (float offsets): SgTp 0 (36864) | Sg2Tp 36864 | XT 73728 (6144)
//  G 79872: GE1@79872(192) GE2@80064(6144) GD1@86208(6144) GD2@92352(192)
//  ZB1 104832 (49152) | ZB2 153984 | ZA1 203136 (98304) | ZA2 301440
//  ZC1 399744 (98304) | ZC2 498048 | B1 596352 | B2 645504 | B3 694656 (49152 ea)

#define NODES 192
typedef float4 f4;

__device__ __forceinline__ void compute_c(const float* __restrict__ s, float c[3][3][3]) {
    const float s00 = s[0], s01 = s[1], s10 = s[2], s11 = s[3];
    #pragma unroll
    for (int k = 0; k < 3; ++k)
        #pragma unroll
        for (int d = 0; d < 3; ++d)
            #pragma unroll
            for (int p = 0; p < 3; ++p) c[k][d][p] = 0.f;
    c[0][0][0] = 1.f;
    c[1][0][0] = s00; c[1][0][1] = s01;
    c[1][1][0] = s10; c[1][1][1] = s11;
    c[2][0][0] = s00 * s00;       c[2][0][1] = 2.f * s00 * s01;               c[2][0][2] = s01 * s01;
    c[2][1][0] = 2.f * s00 * s10; c[2][1][1] = 2.f * (s00 * s11 + s01 * s10); c[2][1][2] = 2.f * s11 * s01;
    c[2][2][0] = s10 * s10;       c[2][2][1] = 2.f * s10 * s11;               c[2][2][2] = s11 * s11;
}

// Partial dual GEMV on an LDS buffer of 4 columns: thread (m,q) computes the
// q-th quarter of the dot for all 4 columns; partials to ps; caller reduces.
__device__ __forceinline__ void gemv4q(const f4* __restrict__ Ap, const f4* __restrict__ Bp,
                                       const float* __restrict__ xs, int m, int q,
                                       float* __restrict__ ps) {
    f4 va[12], vb[12];
    #pragma unroll
    for (int j = 0; j < 12; ++j) va[j] = Ap[(12 * q + j) * NODES + m];
    #pragma unroll
    for (int j = 0; j < 12; ++j) vb[j] = Bp[(12 * q + j) * NODES + m];
    #pragma unroll
    for (int ch = 0; ch < 4; ++ch) {
        const f4* xr = (const f4*)(xs + ch * NODES);
        float a1 = 0.f, a2 = 0.f;
        #pragma unroll
        for (int j = 0; j < 12; ++j) {
            const f4 x = xr[12 * q + j];
            a1 += va[j].x * x.x + va[j].y * x.y + va[j].z * x.z + va[j].w * x.w;
            a2 += vb[j].x * x.x + vb[j].y * x.y + vb[j].z * x.z + vb[j].w * x.w;
        }
        ps[((0 * 4 + ch) * 4 + q) * NODES + m] = a1;
        ps[((1 * 4 + ch) * 4 + q) * NODES + m] = a2;
    }
}

// ---------- K0 prep: b<192 {SgTp pack + Sg^2 row}; b==192 g; b==193 XT ----------
__global__ __launch_bounds__(768) void prep_kernel(
        const float* __restrict__ X, const float* __restrict__ Sg, const float* __restrict__ s,
        const float* __restrict__ he1, const float* __restrict__ he2,
        const float* __restrict__ hd1, const float* __restrict__ hd2,
        float* __restrict__ ws) {
    const int b = blockIdx.x, tid = threadIdx.x;
    float* SgTp  = ws;
    float* Sg2Tp = ws + 36864;
    float* XT    = ws + 73728;
    float* G     = ws + 79872;
    if (b < 192) {
        __shared__ float row[NODES];
        __shared__ float ps[4 * NODES];
        if (tid < NODES) {
            const float v = Sg[b * NODES + tid];
            row[tid] = v;
            SgTp[(tid >> 2) * 768 + b * 4 + (tid & 3)] = v;
        }
        __syncthreads();
        const int n = tid % NODES, q = tid / NODES;
        float v[48];
        #pragma unroll
        for (int rr = 0; rr < 48; ++rr) v[rr] = Sg[(48 * q + rr) * NODES + n];
        float acc = 0.f;
        #pragma unroll
        for (int rr = 0; rr < 48; ++rr) acc += row[48 * q + rr] * v[rr];
        ps[q * NODES + n] = acc;
        __syncthreads();
        if (q == 0) {
            const float s2 = ps[n] + ps[NODES + n] + ps[2 * NODES + n] + ps[3 * NODES + n];
            Sg2Tp[(n >> 2) * 768 + b * 4 + (n & 3)] = s2;
        }
    } else if (b == 192) {
        float c[3][3][3];
        compute_c(s, c);
        for (int w = tid; w < 1056; w += 768) {
            const float* hh; int gbase, pl;
            if (w < 16)        { hh = he1; gbase = 0;     pl = w; }
            else if (w < 528)  { hh = he2; gbase = 192;   pl = w - 16; }
            else if (w < 1040) { hh = hd1; gbase = 6336;  pl = w - 528; }
            else               { hh = hd2; gbase = 12480; pl = w - 1040; }
            const float h0 = hh[pl * 3], h1 = hh[pl * 3 + 1], h2 = hh[pl * 3 + 2];
            float* gp = G + gbase + pl * 12;
            #pragma unroll
            for (int dp = 0; dp < 12; ++dp) {
                float val = 0.f;
                if (dp < 9) { const int d = dp / 3, p = dp % 3;
                              val = h0 * c[0][d][p] + h1 * c[1][d][p] + h2 * c[2][d][p]; }
                gp[dp] = val;
            }
        }
    } else {
        if (tid < NODES) {
            const f4* xr = (const f4*)(X + tid * 32);
            f4 vv[8];
            #pragma unroll
            for (int qq = 0; qq < 8; ++qq) vv[qq] = xr[qq];
            #pragma unroll
            for (int qq = 0; qq < 8; ++qq) {
                XT[(4 * qq + 0) * NODES + tid] = vv[qq].x;
                XT[(4 * qq + 1) * NODES + tid] = vv[qq].y;
                XT[(4 * qq + 2) * NODES + tid] = vv[qq].z;
                XT[(4 * qq + 3) * NODES + tid] = vv[qq].w;
            }
        }
    }
}

// ---------- K1 e1: in-block Zx + conv + pool/relu -> B1; ZB GEMV -> ZB ----------
// 64 blocks = 16 tq x 4 o-chunks, 768 thr = (m, q).
__global__ __launch_bounds__(768) void e1_ker(
        const float* __restrict__ ws_c, float* __restrict__ B1,
        float* __restrict__ Zb1, float* __restrict__ Zb2) {
    const float* XT  = ws_c + 73728;
    const float* GE1 = ws_c + 79872;
    const f4* Ap = (const f4*)(ws_c);
    const f4* Bp = (const f4*)(ws_c + 36864);
    const int b = blockIdx.x, tid = threadIdx.x;
    const int m = tid % NODES, q = tid / NODES;
    const int tq = b & 15, o0 = (b >> 4) * 4;
    __shared__ __align__(16) float sm_x[4 * NODES];
    __shared__ __align__(16) float sm_v[4 * NODES];
    __shared__ __align__(16) float sm_zx1[4 * NODES];
    __shared__ __align__(16) float sm_zx2[4 * NODES];
    __shared__ __align__(16) float sm_g[48];
    __shared__ __align__(16) float sm_ps[8 * 4 * NODES];
    {
        const int u = (2 * tq + q - 2) & 31;
        sm_x[q * NODES + m] = XT[u * NODES + m];
    }
    if (tid < 48) sm_g[tid] = GE1[o0 * 12 + tid];
    __syncthreads();
    gemv4q(Ap, Bp, sm_x, m, q, sm_ps);
    __syncthreads();
    {
        #pragma unroll
        for (int pp = 0; pp < 2; ++pp) {
            const int pi = q * 2 + pp, mat = pi >> 2, ch = pi & 3;
            float val = 0.f;
            #pragma unroll
            for (int qq = 0; qq < 4; ++qq)
                val += sm_ps[((mat * 4 + ch) * 4 + qq) * NODES + m];
            (mat == 0 ? sm_zx1 : sm_zx2)[ch * NODES + m] = val;
        }
    }
    __syncthreads();
    {
        float x0[4], z1[4], z2[4];
        #pragma unroll
        for (int dl = 0; dl < 4; ++dl) {
            x0[dl] = sm_x[dl * NODES + m];
            z1[dl] = sm_zx1[dl * NODES + m];
            z2[dl] = sm_zx2[dl * NODES + m];
        }
        const float* gr = &sm_g[q * 12];
        const f4 ga = *(const f4*)gr, gb = *(const f4*)(gr + 4), gc = *(const f4*)(gr + 8);
        float a[2];
        #pragma unroll
        for (int tt = 0; tt < 2; ++tt)
            a[tt] = ga.x * x0[tt + 2] + ga.y * z1[tt + 2] + ga.z * z2[tt + 2]
                  + ga.w * x0[tt + 1] + gb.x * z1[tt + 1] + gb.y * z2[tt + 1]
                  + gb.z * x0[tt]     + gb.w * z1[tt]     + gc.x * z2[tt];
        const float v = fmaxf(fmaxf(a[0], a[1]), 0.f);
        B1[(tq * 16 + o0 + q) * NODES + m] = v;
        sm_v[q * NODES + m] = v;
    }
    __syncthreads();
    gemv4q(Ap, Bp, sm_v, m, q, sm_ps);
    __syncthreads();
    {
        #pragma unroll
        for (int pp = 0; pp < 2; ++pp) {
            const int pi = q * 2 + pp, mat = pi >> 2, ch = pi & 3;
            float val = 0.f;
            #pragma unroll
            for (int qq = 0; qq < 4; ++qq)
                val += sm_ps[((mat * 4 + ch) * 4 + qq) * NODES + m];
            (mat == 0 ? Zb1 : Zb2)[(tq * 16 + o0 + ch) * NODES + m] = val;
        }
    }
}

// ---------- K2 e2: conv -> B2; ZA GEMV (zero-stuffed T=16) ----------
// 64 blocks = 8 q8 x 8 o-chunks of 4, 768 thr = (m, q).
__global__ __launch_bounds__(768) void e2_ker(
        const float* __restrict__ ws_c,
        const float* __restrict__ B1, const float* __restrict__ Zb1, const float* __restrict__ Zb2,
        float* __restrict__ B2, float* __restrict__ Za1, float* __restrict__ Za2) {
    const float* GE2 = ws_c + 80064;
    const f4* Ap = (const f4*)(ws_c);
    const f4* Bp = (const f4*)(ws_c + 36864);
    const int b = blockIdx.x, tid = threadIdx.x;
    const int m = tid % NODES, q = tid / NODES;
    const int q8 = b & 7, o0 = (b >> 3) * 4;
    __shared__ __align__(16) float sm_g[768];
    __shared__ __align__(16) float sm_v[4 * NODES];
    __shared__ __align__(16) float sm_ps[8 * 4 * NODES];
    sm_g[tid] = GE2[o0 * 16 * 12 + tid];
    {
        const int i0 = q * 4;
        float xv[4][4], z1v[4][4], z2v[4][4];
        #pragma unroll
        for (int dl = 0; dl < 4; ++dl) {
            const int u = (2 * q8 + dl - 2) & 15;
            const int base = (u * 16 + i0) * NODES + m;
            #pragma unroll
            for (int ii = 0; ii < 4; ++ii) xv[dl][ii]  = B1[base + ii * NODES];
            #pragma unroll
            for (int ii = 0; ii < 4; ++ii) z1v[dl][ii] = Zb1[base + ii * NODES];
            #pragma unroll
            for (int ii = 0; ii < 4; ++ii) z2v[dl][ii] = Zb2[base + ii * NODES];
        }
        __syncthreads();   // sm_g ready
        #pragma unroll
        for (int o = 0; o < 4; ++o) {
            float a[2] = {0.f, 0.f};
            #pragma unroll
            for (int ii = 0; ii < 4; ++ii) {
                const float* gr = &sm_g[(o * 16 + i0 + ii) * 12];
                const f4 ga = *(const f4*)gr, gb = *(const f4*)(gr + 4), gc = *(const f4*)(gr + 8);
                #pragma unroll
                for (int tt = 0; tt < 2; ++tt)
                    a[tt] += ga.x * xv[tt + 2][ii] + ga.y * z1v[tt + 2][ii] + ga.z * z2v[tt + 2][ii]
                           + ga.w * xv[tt + 1][ii] + gb.x * z1v[tt + 1][ii] + gb.y * z2v[tt + 1][ii]
                           + gb.z * xv[tt][ii]     + gb.w * z1v[tt][ii]     + gc.x * z2v[tt][ii];
            }
            sm_ps[((q * 4 + o) * 2 + 0) * NODES + m] = a[0];
            sm_ps[((q * 4 + o) * 2 + 1) * NODES + m] = a[1];
        }
    }
    __syncthreads();
    {
        float r0 = 0.f, r1 = 0.f;
        #pragma unroll
        for (int cq = 0; cq < 4; ++cq) {
            r0 += sm_ps[((cq * 4 + q) * 2 + 0) * NODES + m];
            r1 += sm_ps[((cq * 4 + q) * 2 + 1) * NODES + m];
        }
        const float v = fmaxf(fmaxf(r0, r1), 0.f);
        B2[(q8 * 32 + o0 + q) * NODES + m] = v;
        sm_v[q * NODES + m] = v;
    }
    __syncthreads();
    gemv4q(Ap, Bp, sm_v, m, q, sm_ps);
    __syncthreads();
    {
        const int t2 = 2 * q8;
        #pragma unroll
        for (int pp = 0; pp < 2; ++pp) {
            const int pi = q * 2 + pp, mat = pi >> 2, ch = pi & 3;
            float val = 0.f;
            #pragma unroll
            for (int qq = 0; qq < 4; ++qq)
                val += sm_ps[((mat * 4 + ch) * 4 + qq) * NODES + m];
            float* Z = (mat == 0) ? Za1 : Za2;
            Z[(t2 * 32 + o0 + ch) * NODES + m] = val;
            Z[((t2 + 1) * 32 + o0 + ch) * NODES + m] = 0.f;
        }
    }
}

// ---------- K3 d1: conv (relu(up(B2))) -> B3 raw; ZC GEMV (zero-stuffed T=32) ----------
// 64 blocks = 16 t x 4 o-chunks of 4, 768 thr = (m, q).
__global__ __launch_bounds__(768) void d1_ker(
        const float* __restrict__ ws_c,
        const float* __restrict__ B2, const float* __restrict__ Za1, const float* __restrict__ Za2,
        float* __restrict__ B3, float* __restrict__ Zc1, float* __restrict__ Zc2) {
    const float* GD1 = ws_c + 86208;
    const f4* Ap = (const f4*)(ws_c);
    const f4* Bp = (const f4*)(ws_c + 36864);
    const int b = blockIdx.x, tid = threadIdx.x;
    const int m = tid % NODES, q = tid / NODES;
    const int t16 = b & 15, o0 = (b >> 4) * 4;
    __shared__ __align__(16) float sm_g[1536];
    __shared__ __align__(16) float sm_v[4 * NODES];
    __shared__ __align__(16) float sm_ps[8 * 4 * NODES];
    for (int idx = tid; idx < 1536; idx += 768) sm_g[idx] = GD1[o0 * 32 * 12 + idx];
    __syncthreads();
    {
        float acc[4] = {0.f, 0.f, 0.f, 0.f};
        #pragma unroll
        for (int cc = 0; cc < 2; ++cc) {
            const int i0 = cc * 16 + q * 4;
            float xv[3][4], z1v[3][4], z2v[3][4];
            #pragma unroll
            for (int dl = 0; dl < 3; ++dl) {
                const int u = (t16 + dl - 2) & 15;
                const float msk = (u & 1) ? 0.f : 1.f;
                const int sb = ((u >> 1) * 32 + i0) * NODES + m;
                const int zb = (u * 32 + i0) * NODES + m;
                #pragma unroll
                for (int ii = 0; ii < 4; ++ii) xv[dl][ii]  = B2[sb + ii * NODES] * msk;  // B2>=0
                #pragma unroll
                for (int ii = 0; ii < 4; ++ii) z1v[dl][ii] = Za1[zb + ii * NODES];
                #pragma unroll
                for (int ii = 0; ii < 4; ++ii) z2v[dl][ii] = Za2[zb + ii * NODES];
            }
            #pragma unroll
            for (int o = 0; o < 4; ++o)
                #pragma unroll
                for (int ii = 0; ii < 4; ++ii) {
                    const float* gr = &sm_g[(o * 32 + i0 + ii) * 12];
                    const f4 ga = *(const f4*)gr, gb = *(const f4*)(gr + 4), gc = *(const f4*)(gr + 8);
                    acc[o] += ga.x * xv[2][ii] + ga.y * z1v[2][ii] + ga.z * z2v[2][ii]
                            + ga.w * xv[1][ii] + gb.x * z1v[1][ii] + gb.y * z2v[1][ii]
                            + gb.z * xv[0][ii] + gb.w * z1v[0][ii] + gc.x * z2v[0][ii];
                }
        }
        #pragma unroll
        for (int o = 0; o < 4; ++o) sm_ps[(q * 4 + o) * NODES + m] = acc[o];
    }
    __syncthreads();
    {
        const float raw = sm_ps[(0 * 4 + q) * NODES + m] + sm_ps[(1 * 4 + q) * NODES + m]
                        + sm_ps[(2 * 4 + q) * NODES + m] + sm_ps[(3 * 4 + q) * NODES + m];
        B3[(t16 * 16 + o0 + q) * NODES + m] = raw;
        sm_v[q * NODES + m] = fmaxf(raw, 0.f);
    }
    __syncthreads();
    gemv4q(Ap, Bp, sm_v, m, q, sm_ps);
    __syncthreads();
    {
        const int t2 = 2 * t16;
        #pragma unroll
        for (int pp = 0; pp < 2; ++pp) {
            const int pi = q * 2 + pp, mat = pi >> 2, ch = pi & 3;
            float val = 0.f;
            #pragma unroll
            for (int qq = 0; qq < 4; ++qq)
                val += sm_ps[((mat * 4 + ch) * 4 + qq) * NODES + m];
            float* Z = (mat == 0) ? Zc1 : Zc2;
            Z[(t2 * 16 + o0 + ch) * NODES + m] = val;
            Z[((t2 + 1) * 16 + o0 + ch) * NODES + m] = 0.f;
        }
    }
}

// ---------- K4 d2: conv (relu(up(B3))) -> out[m*32+t]. 32 blocks ----------
__global__ __launch_bounds__(768) void d2_ker(
        const float* __restrict__ ws_c,
        const float* __restrict__ B3, const float* __restrict__ Zc1, const float* __restrict__ Zc2,
        float* __restrict__ out) {
    const float* GD2 = ws_c + 92352;
    const int t = blockIdx.x, tid = threadIdx.x;
    const int m = tid % NODES, q = tid / NODES;
    __shared__ __align__(16) float sm_g[192];
    __shared__ float sm_ps[4 * NODES];
    if (tid < 192) sm_g[tid] = GD2[tid];
    {
        const int i0 = q * 4;
        float xv[3][4], z1v[3][4], z2v[3][4];
        #pragma unroll
        for (int dl = 0; dl < 3; ++dl) {
            const int u = (t + dl - 2) & 31;
            const float msk = (u & 1) ? 0.f : 1.f;
            const int sb = ((u >> 1) * 16 + i0) * NODES + m;
            const int zb = (u * 16 + i0) * NODES + m;
            #pragma unroll
            for (int ii = 0; ii < 4; ++ii) xv[dl][ii]  = fmaxf(B3[sb + ii * NODES], 0.f) * msk;
            #pragma unroll
            for (int ii = 0; ii < 4; ++ii) z1v[dl][ii] = Zc1[zb + ii * NODES];
            #pragma unroll
            for (int ii = 0; ii < 4; ++ii) z2v[dl][ii] = Zc2[zb + ii * NODES];
        }
        __syncthreads();   // sm_g ready
        float acc = 0.f;
        #pragma unroll
        for (int ii = 0; ii < 4; ++ii) {
            const float* gr = &sm_g[(i0 + ii) * 12];
            const f4 ga = *(const f4*)gr, gb = *(const f4*)(gr + 4), gc = *(const f4*)(gr + 8);
            acc += ga.x * xv[2][ii] + ga.y * z1v[2][ii] + ga.z * z2v[2][ii]
                 + ga.w * xv[1][ii] + gb.x * z1v[1][ii] + gb.y * z2v[1][ii]
                 + gb.z * xv[0][ii] + gb.w * z1v[0][ii] + gc.x * z2v[0][ii];
        }
        sm_ps[q * NODES + m] = acc;
    }
    __syncthreads();
    if (q == 0)
        out[m * 32 + t] = sm_ps[m] + sm_ps[NODES + m] + sm_ps[2 * NODES + m] + sm_ps[3 * NODES + m];
}

extern "C" void kernel_launch(void* const* d_in, const int* in_sizes, int n_in,
                              void* d_out, int out_size, void* d_ws, size_t ws_size,
                              hipStream_t stream) {
    (void)in_sizes; (void)n_in; (void)out_size; (void)ws_size;
    const float* X   = (const float*)d_in[0];
    const float* Sg  = (const float*)d_in[1];
    const float* s   = (const float*)d_in[2];
    const float* he1 = (const float*)d_in[3];
    const float* he2 = (const float*)d_in[4];
    const float* hd1 = (const float*)d_in[5];
    const float* hd2 = (const float*)d_in[6];
    float* out = (float*)d_out;
    float* ws  = (float*)d_ws;

    float* ZB1 = ws + 104832, *ZB2 = ws + 153984;
    float* ZA1 = ws + 203136, *ZA2 = ws + 301440;
    float* ZC1 = ws + 399744, *ZC2 = ws + 498048;
    float* B1  = ws + 596352, *B2 = ws + 645504, *B3 = ws + 694656;

    prep_kernel<<<194, 768, 0, stream>>>(X, Sg, s, he1, he2, hd1, hd2, ws);
    e1_ker<<<64, 768, 0, stream>>>(ws, B1, ZB1, ZB2);
    e2_ker<<<64, 768, 0, stream>>>(ws, B1, ZB1, ZB2, B2, ZA1, ZA2);
    d1_ker<<<64, 768, 0, stream>>>(ws, B2, ZA1, ZA2, B3, ZC1, ZC2);
    d2_ker<<<32, 768, 0, stream>>>(ws, B3, ZC1, ZC2, out);
}